// Round 10
// baseline (5696.525 us; speedup 1.0000x reference)
//
#include <hip/hip_runtime.h>
#include <hip/hip_bf16.h>
#include <math.h>

#define TSTEPS 1024

typedef __attribute__((ext_vector_type(8))) short short8;
typedef __attribute__((ext_vector_type(4))) float f32x4;
typedef __attribute__((ext_vector_type(4))) unsigned u32x4;

// ---- workspace layout (float units) ----
#define WS_BAR     0
#define WS_WEFF_C  1024
#define WS_WEFF_X  (WS_WEFF_C + 20480)
#define WS_BIAS_C  (WS_WEFF_X + 12288)
#define WS_BIAS_X  (WS_BIAS_C + 131072)
#define WS_HRING   (WS_BIAS_X + 131072)    // uints: 8 islands * 8 slots * 8192 = 524288 (2MB, memset/launch)
#define WS_WPACK   (WS_HRING + 524288)     // shorts: 4194304 -> 2097152 floats
#define WS_WHEAD   (WS_WPACK + 2097152)    // shorts: 16384 -> 8192 floats

__device__ __forceinline__ float sigm(float v) { return 1.f / (1.f + __expf(-v)); }

// LDS-only barrier: order ds ops without draining in-flight global stores.
__device__ __forceinline__ void bar_lds() {
    asm volatile("s_waitcnt lgkmcnt(0)\n\ts_barrier" ::: "memory");
}

// ---------------- setup 1: effective input weights + per-batch bias (validated R1-R9) ----------------
__global__ void setup_weff_bias(const float* __restrict__ ctx,
                                const float* __restrict__ we_c, const float* __restrict__ be_c,
                                const float* __restrict__ we_x, const float* __restrict__ be_x,
                                const float* __restrict__ wih_c, const float* __restrict__ bih_c, const float* __restrict__ bhh_c,
                                const float* __restrict__ wih_x, const float* __restrict__ bih_x, const float* __restrict__ bhh_x,
                                float* __restrict__ weff_c_o, float* __restrict__ weff_x_o,
                                float* __restrict__ biasE_c_o, float* __restrict__ biasE_x_o)
{
    const int g = blockIdx.x;
    const int lstm = blockIdx.y;
    const int tid = threadIdx.x;
    const float* wih  = lstm ? wih_x : wih_c;
    const float* wemb = lstm ? we_x  : we_c;
    const float* bemb = lstm ? be_x  : be_c;
    const int NW = lstm ? 6 : 10;
    float* weff  = lstm ? weff_x_o  : weff_c_o;
    float* biasE = lstm ? biasE_x_o : biasE_c_o;
    const float* wg_ = wih + (size_t)g * 768;

    __shared__ float s_bias0;

    if (tid < NW) {
        float s = 0.f;
        for (int d = 0; d < 512; ++d) s = fmaf(wg_[d], wemb[d * NW + tid], s);
        weff[g * NW + tid] = s;
    }
    if (tid >= 64 && tid < 128) {
        int l = tid - 64;
        float s = 0.f;
        for (int i = 0; i < 8; ++i) { int d = l + i * 64; s = fmaf(wg_[d], bemb[d], s); }
        for (int m = 1; m < 64; m <<= 1) s += __shfl_xor(s, m);
        if (l == 0) s_bias0 = s;
    }
    __syncthreads();
    if (tid >= 128 && tid < 192) {
        int b = tid - 128;
        float s = s_bias0 + (lstm ? (bih_x[g] + bhh_x[g]) : (bih_c[g] + bhh_c[g]));
        const float* cb = ctx + b * 256;
        const float* wc = wg_ + 512;
        for (int c = 0; c < 256; ++c) s = fmaf(wc[c], cb[c], s);
        biasE[b * 2048 + g] = s;
    }
}

// ---------------- setup 2: pack W_hh into MFMA B-frag layout, bf16 hi/lo (validated R3-R9) ----------------
__global__ void setup_wpackF(const float* __restrict__ whh_c, const float* __restrict__ whh_x,
                             short* __restrict__ wpackF)
{
    int idx = blockIdx.x * 256 + threadIdx.x;      // 2^21 total
    int pos = idx & 511;
    int lane = pos >> 3, j = pos & 7;
    int kt4 = (idx >> 9) & 3;
    int q   = (idx >> 11) & 3;
    int wv  = (idx >> 13) & 3;
    int ub  = (idx >> 15) & 31;
    int lstm = (idx >> 20) & 1;
    int g = q * 512 + ub * 16 + (lane & 15);
    int k = wv * 128 + kt4 * 32 + (lane >> 4) * 8 + j;
    const float* whh = lstm ? whh_x : whh_c;
    float v = whh[(size_t)g * 512 + k];
    __hip_bfloat16 hi = __float2bfloat16(v);
    __hip_bfloat16 lo = __float2bfloat16(v - __bfloat162float(hi));
    size_t base = (size_t)(idx >> 9) * 1024 + pos;
    wpackF[base]       = __builtin_bit_cast(short, hi);
    wpackF[base + 512] = __builtin_bit_cast(short, lo);
}

// ---------------- setup 3: pack head weights into B-frag layout (hi only, validated R8) ----------------
__global__ void setup_wheadF(const float* __restrict__ w_out_cmd,
                             const float* __restrict__ w_out_coord,
                             short* __restrict__ wheadF)
{
    int idx = blockIdx.x * 256 + threadIdx.x;      // 16384 total
    int lstm = idx >> 13;
    int rest = idx & 8191;
    int wv = rest >> 11;
    int k4 = (rest >> 9) & 3;
    int pos = rest & 511;
    int lane = pos >> 3, jj = pos & 7;
    int j = lane & 15;
    int k = wv * 128 + k4 * 32 + (lane >> 4) * 8 + jj;
    int NJ = lstm ? 6 : 10;
    float v = 0.f;
    if (j < NJ) v = lstm ? w_out_coord[(size_t)j * 522 + k] : w_out_cmd[(size_t)j * 512 + k];
    wheadF[idx] = __builtin_bit_cast(short, __float2bfloat16(v));
}

// ---------------- main persistent kernel ----------------
// 128 WGs x 256 thr, 1 WG/CU. Island = (lstm, bt): SIXTEEN WGs, each owning 32 units x 16 batches
// (W frags for 2 unit-groups live in the unified VGPR/AGPR file, launch_bounds(256,1) -> 512 regs).
// Protocol identical to validated R8: depth-8 ring, epoch tag (2 bits of lo mantissa) = 1+((t>>3)&1),
// tag-retry wide coherent loads, per-thread tagged agent-scope atomic stores, lgkm-only barriers.
// Heads rotate over ub == (tc & 15): head MFMA pre-barrier, head epilogue post-publish (R8 placement).
__global__ __launch_bounds__(256, 1) void lstm_main(
    const float* __restrict__ x,
    const short* __restrict__ wpackF,
    const short* __restrict__ wheadF,
    const float* __restrict__ weff_c, const float* __restrict__ weff_x,
    const float* __restrict__ biasE_c, const float* __restrict__ biasE_x,
    unsigned* __restrict__ ring,
    const float* __restrict__ b_out_cmd, const float* __restrict__ b_out_coord,
    float* __restrict__ pre_coord,
    float* __restrict__ out)
{
    __shared__ float lds_gp[2][4][4][16][17];   // [half][wv][q][b][u] gate partials
    __shared__ float lds_hp[4][16][17];         // [wv][b][j] head partials
    __shared__ float x_lds[16][10];
    __shared__ float weff_lds[4][32][10];
    __shared__ short whd_lds[4][4][512];        // head B-frags [wv][k4][...]

    const int tid = threadIdx.x;
    const int bid = blockIdx.x;
    const int lane = tid & 63;
    const int wv = tid >> 6;
    const int lstm = bid >> 6;
    const int ub = (bid >> 2) & 15;             // 16 WGs per island
    const int bt = bid & 3;
    const int island = lstm * 4 + bt;
    const int u0 = ub * 32, b0 = bt * 16;
    const int NW = lstm ? 6 : 10;
    const int xoff = lstm ? 10 : 0;
    const int u_l = tid & 15, b_l = tid >> 4;

    const float* weff  = lstm ? weff_x : weff_c;
    const float* biasE = lstm ? biasE_x : biasE_c;

    unsigned* ring_isl = ring + island * 8 * 8192;   // 8 slots x 8192 uints

    // ---- one-time: recurrent weight frags (2 unit-groups) into registers/AGPRs ----
    short8 W[2][4][4][2];
#pragma unroll
    for (int hf = 0; hf < 2; ++hf) {
        const short* wbh = wpackF + (size_t)(((lstm * 32 + ub * 2 + hf) * 4 + wv) * 16) * 1024 + lane * 8;
#pragma unroll
        for (int q = 0; q < 4; ++q)
#pragma unroll
            for (int k4 = 0; k4 < 4; ++k4) {
                W[hf][q][k4][0] = *(const short8*)(wbh + (q * 4 + k4) * 1024);
                W[hf][q][k4][1] = *(const short8*)(wbh + (q * 4 + k4) * 1024 + 512);
            }
    }

    float biasr[2][4];
#pragma unroll
    for (int hf = 0; hf < 2; ++hf)
#pragma unroll
        for (int q = 0; q < 4; ++q)
            biasr[hf][q] = biasE[(size_t)(b0 + b_l) * 2048 + q * 512 + u0 + hf * 16 + u_l];

    for (int i = tid; i < 128 * NW; i += 256) {
        int r = i / NW, j = i - r * NW;
        int q = r >> 5, u = r & 31;
        weff_lds[q][u][j] = weff[(size_t)(q * 512 + u0 + u) * NW + j];
    }

    // head staging: ALL WGs rotate as head
    float hbias = 0.f;
    const int NJ = lstm ? 6 : 10;
    if (u_l < NJ) hbias = lstm ? b_out_coord[u_l] : b_out_cmd[u_l];
    {
        const short* src = wheadF + lstm * 8192;
        short* dst = &whd_lds[0][0][0];
        for (int i = tid; i < 8192; i += 256) dst[i] = src[i];
    }

    float c_reg[2] = {0.f, 0.f};
    __syncthreads();   // one-time staging barrier

    for (int t = 0; t <= TSTEPS; ++t) {
        const bool last = (t == TSTEPS);
        if (last && ub != 15) break;   // only the tc=1023 head WG runs the final step

        // ---- x prefetch for step t ----
        float xv = 0.f;
        int xb = 0, xj = 0;
        const bool hasx = !last && (tid < 16 * NW);
        if (hasx) {
            xb = tid / NW; xj = tid - xb * NW;
            xv = x[(size_t)((b0 + xb) * TSTEPS + t) * 16 + xoff + xj];
        }

        // ---- A-frags: epoch-tagged retry load of h_{t-1} (validated R8) ----
        short8 Ah[4], Al[4];
        if (t > 0) {
            const unsigned rtag = 1u + (((unsigned)(t - 1) >> 3) & 1u);
            const unsigned* rb = ring_isl + ((t + 7) & 7) * 8192 + lane * 8;
            const unsigned* p0 = rb + (wv * 4 + 0) * 512;
            const unsigned* p1 = rb + (wv * 4 + 1) * 512;
            const unsigned* p2 = rb + (wv * 4 + 2) * 512;
            const unsigned* p3 = rb + (wv * 4 + 3) * 512;
            u32x4 r0, r1, r2, r3, r4, r5, r6, r7;
            while (true) {
                asm volatile(
                    "global_load_dwordx4 %0, %8, off sc0 sc1\n\t"
                    "global_load_dwordx4 %1, %8, off offset:16 sc0 sc1\n\t"
                    "global_load_dwordx4 %2, %9, off sc0 sc1\n\t"
                    "global_load_dwordx4 %3, %9, off offset:16 sc0 sc1\n\t"
                    "global_load_dwordx4 %4, %10, off sc0 sc1\n\t"
                    "global_load_dwordx4 %5, %10, off offset:16 sc0 sc1\n\t"
                    "global_load_dwordx4 %6, %11, off sc0 sc1\n\t"
                    "global_load_dwordx4 %7, %11, off offset:16 sc0 sc1\n\t"
                    "s_waitcnt vmcnt(0)"
                    : "=&v"(r0), "=&v"(r1), "=&v"(r2), "=&v"(r3),
                      "=&v"(r4), "=&v"(r5), "=&v"(r6), "=&v"(r7)
                    : "v"(p0), "v"(p1), "v"(p2), "v"(p3)
                    : "memory");
                bool ok = true;
#pragma unroll
                for (int e = 0; e < 4; ++e) {
                    ok = ok && (((r0[e] >> 16) & 3u) == rtag) && (((r1[e] >> 16) & 3u) == rtag)
                            && (((r2[e] >> 16) & 3u) == rtag) && (((r3[e] >> 16) & 3u) == rtag)
                            && (((r4[e] >> 16) & 3u) == rtag) && (((r5[e] >> 16) & 3u) == rtag)
                            && (((r6[e] >> 16) & 3u) == rtag) && (((r7[e] >> 16) & 3u) == rtag);
                }
                if (__all((int)ok)) break;
            }
            unsigned uu[4][8];
#pragma unroll
            for (int e = 0; e < 4; ++e) {
                uu[0][e] = r0[e]; uu[0][4 + e] = r1[e];
                uu[1][e] = r2[e]; uu[1][4 + e] = r3[e];
                uu[2][e] = r4[e]; uu[2][4 + e] = r5[e];
                uu[3][e] = r6[e]; uu[3][4 + e] = r7[e];
            }
#pragma unroll
            for (int i = 0; i < 4; ++i) {
                union { unsigned u[4]; short8 s; } ah, al;
                ah.u[0] = __builtin_amdgcn_perm(uu[i][1], uu[i][0], 0x05040100u);
                ah.u[1] = __builtin_amdgcn_perm(uu[i][3], uu[i][2], 0x05040100u);
                ah.u[2] = __builtin_amdgcn_perm(uu[i][5], uu[i][4], 0x05040100u);
                ah.u[3] = __builtin_amdgcn_perm(uu[i][7], uu[i][6], 0x05040100u);
                al.u[0] = __builtin_amdgcn_perm(uu[i][1], uu[i][0], 0x07060302u);
                al.u[1] = __builtin_amdgcn_perm(uu[i][3], uu[i][2], 0x07060302u);
                al.u[2] = __builtin_amdgcn_perm(uu[i][5], uu[i][4], 0x07060302u);
                al.u[3] = __builtin_amdgcn_perm(uu[i][7], uu[i][6], 0x07060302u);
                Ah[i] = ah.s;
                Al[i] = al.s;
            }
        }

        // ---- gates MFMA (both unit-halves) ----
        if (!last) {
            f32x4 C[2][4];
#pragma unroll
            for (int hf = 0; hf < 2; ++hf)
#pragma unroll
                for (int q = 0; q < 4; ++q) { C[hf][q][0] = 0.f; C[hf][q][1] = 0.f; C[hf][q][2] = 0.f; C[hf][q][3] = 0.f; }
            if (t > 0) {
#pragma unroll
                for (int hf = 0; hf < 2; ++hf)
#pragma unroll
                    for (int q = 0; q < 4; ++q)
#pragma unroll
                        for (int i = 0; i < 4; ++i) {
                            C[hf][q] = __builtin_amdgcn_mfma_f32_16x16x32_bf16(Ah[i], W[hf][q][i][0], C[hf][q], 0, 0, 0);
                            C[hf][q] = __builtin_amdgcn_mfma_f32_16x16x32_bf16(Al[i], W[hf][q][i][0], C[hf][q], 0, 0, 0);
                            C[hf][q] = __builtin_amdgcn_mfma_f32_16x16x32_bf16(Ah[i], W[hf][q][i][1], C[hf][q], 0, 0, 0);
                        }
            }
#pragma unroll
            for (int hf = 0; hf < 2; ++hf)
#pragma unroll
                for (int q = 0; q < 4; ++q)
#pragma unroll
                    for (int i = 0; i < 4; ++i)
                        lds_gp[hf][wv][q][(lane >> 4) * 4 + i][lane & 15] = C[hf][q][i];
            if (hasx) x_lds[xb][xj] = xv;
        }

        // ---- rotating head MFMA (WG ub == tc&15): reuses A-frags, hi-only ----
        const bool hd = (t > 0) && (ub == ((t - 1) & 15));
        if (hd) {
            short8 Whd[4];
#pragma unroll
            for (int i = 0; i < 4; ++i)
                Whd[i] = *(const short8*)&whd_lds[wv][i][lane * 8];
            f32x4 Ch; Ch[0] = 0.f; Ch[1] = 0.f; Ch[2] = 0.f; Ch[3] = 0.f;
#pragma unroll
            for (int i = 0; i < 4; ++i)
                Ch = __builtin_amdgcn_mfma_f32_16x16x32_bf16(Ah[i], Whd[i], Ch, 0, 0, 0);
#pragma unroll
            for (int i = 0; i < 4; ++i)
                lds_hp[wv][(lane >> 4) * 4 + i][lane & 15] = Ch[i];
        }
        bar_lds();   // #1: partials + x visible

        // ---- gate epilogue + cell update + tagged ring store (R8 publish, 2 units/thread) ----
        if (!last) {
            const unsigned wtag = 1u + (((unsigned)t >> 3) & 1u);
#pragma unroll
            for (int hf = 0; hf < 2; ++hf) {
                float g4[4];
#pragma unroll
                for (int q = 0; q < 4; ++q) {
                    float s = biasr[hf][q];
                    s += lds_gp[hf][0][q][b_l][u_l] + lds_gp[hf][1][q][b_l][u_l]
                       + lds_gp[hf][2][q][b_l][u_l] + lds_gp[hf][3][q][b_l][u_l];
                    for (int j = 0; j < NW; ++j)
                        s = fmaf(weff_lds[q][hf * 16 + u_l][j], x_lds[b_l][j], s);
                    g4[q] = s;
                }
                float iv = sigm(g4[0]);
                float fv = sigm(g4[1]);
                float gv = tanhf(g4[2]);
                float ov = sigm(g4[3]);
                c_reg[hf] = fmaf(fv, c_reg[hf], iv * gv);
                float hv = ov * tanhf(c_reg[hf]);
                __hip_bfloat16 hh = __float2bfloat16(hv);
                __hip_bfloat16 hl = __float2bfloat16(hv - __bfloat162float(hh));
                unsigned pack = (unsigned)(unsigned short)__builtin_bit_cast(short, hh)
                              | ((unsigned)(unsigned short)__builtin_bit_cast(short, hl) << 16);
                pack = (pack & ~0x00030000u) | (wtag << 16);
                int ug = u0 + hf * 16 + u_l;
                int kt = ug >> 5, ko = ug & 31;
                unsigned idx = (unsigned)((t & 7) * 8192 + kt * 512
                             + ((ko >> 3) * 16 + b_l) * 8 + (ko & 7));
                __hip_atomic_store(&ring_isl[idx], pack, __ATOMIC_RELAXED, __HIP_MEMORY_SCOPE_AGENT);
            }
        }

        // ---- head epilogue (rotating WG): h_{t-1} heads, no extra loads ----
        if (hd && u_l < NJ) {
            float hs = lds_hp[0][b_l][u_l] + lds_hp[1][b_l][u_l]
                     + lds_hp[2][b_l][u_l] + lds_hp[3][b_l][u_l] + hbias;
            const int tc = t - 1;
            if (lstm == 0)
                out[(size_t)((b0 + b_l) * TSTEPS + tc) * 10 + u_l] = hs;
            else
                pre_coord[(size_t)((b0 + b_l) * TSTEPS + tc) * 6 + u_l] = hs;
        }

        bar_lds();   // #2: protect LDS reuse before next iteration's writes
    }
}

// ---------------- post: coord output = tanh(scale * (pre + cmd-coupling)), in place ----------------
__global__ void coord_post(const float* __restrict__ w_oc,
                           const float* __restrict__ scale_p, float* __restrict__ out)
{
    int idx = blockIdx.x * 256 + threadIdx.x;
    if (idx >= 64 * TSTEPS * 6) return;
    int j = idx % 6, bt_ = idx / 6;
    float s = out[64 * TSTEPS * 10 + idx];
    const float* cmd = out + (size_t)bt_ * 10;
#pragma unroll
    for (int i = 0; i < 10; ++i) s = fmaf(cmd[i], w_oc[j * 522 + 512 + i], s);
    out[64 * TSTEPS * 10 + idx] = tanhf(s * scale_p[0]);
}

// ---------------- host launcher ----------------
extern "C" void kernel_launch(void* const* d_in, const int* in_sizes, int n_in,
                              void* d_out, int out_size, void* d_ws, size_t ws_size,
                              hipStream_t stream)
{
    const float* x            = (const float*)d_in[0];
    const float* context      = (const float*)d_in[1];
    const float* w_cmd_emb    = (const float*)d_in[2];
    const float* b_cmd_emb    = (const float*)d_in[3];
    const float* w_coord_emb  = (const float*)d_in[4];
    const float* b_coord_emb  = (const float*)d_in[5];
    const float* w_ih_cmd     = (const float*)d_in[6];
    const float* w_hh_cmd     = (const float*)d_in[7];
    const float* b_ih_cmd     = (const float*)d_in[8];
    const float* b_hh_cmd     = (const float*)d_in[9];
    const float* w_ih_coord   = (const float*)d_in[10];
    const float* w_hh_coord   = (const float*)d_in[11];
    const float* b_ih_coord   = (const float*)d_in[12];
    const float* b_hh_coord   = (const float*)d_in[13];
    const float* w_out_cmd    = (const float*)d_in[14];
    const float* b_out_cmd    = (const float*)d_in[15];
    const float* w_out_coord  = (const float*)d_in[16];
    const float* b_out_coord  = (const float*)d_in[17];
    const float* scale        = (const float*)d_in[18];

    float* ws  = (float*)d_ws;
    float* out = (float*)d_out;

    float* weff_c   = ws + WS_WEFF_C;
    float* weff_x   = ws + WS_WEFF_X;
    float* biasE_c  = ws + WS_BIAS_C;
    float* biasE_x  = ws + WS_BIAS_X;
    unsigned* ring  = (unsigned*)(ws + WS_HRING);
    short* wpackF   = (short*)(ws + WS_WPACK);
    short* wheadF   = (short*)(ws + WS_WHEAD);
    float* pre      = out + 64 * TSTEPS * 10;   // coord pre-activations live in out tail

    // zero the h ring every launch: tag bits of zeroed words (=0) never match tags {1,2}
    hipMemsetAsync(ring, 0, 8 * 8 * 8192 * sizeof(unsigned), stream);

    setup_weff_bias<<<dim3(2048, 2), 256, 0, stream>>>(
        context, w_cmd_emb, b_cmd_emb, w_coord_emb, b_coord_emb,
        w_ih_cmd, b_ih_cmd, b_hh_cmd,
        w_ih_coord, b_ih_coord, b_hh_coord,
        weff_c, weff_x, biasE_c, biasE_x);

    setup_wpackF<<<8192, 256, 0, stream>>>(w_hh_cmd, w_hh_coord, wpackF);
    setup_wheadF<<<64, 256, 0, stream>>>(w_out_cmd, w_out_coord, wheadF);

    void* args[] = {
        (void*)&x, (void*)&wpackF, (void*)&wheadF,
        (void*)&weff_c, (void*)&weff_x,
        (void*)&biasE_c, (void*)&biasE_x,
        (void*)&ring,
        (void*)&b_out_cmd, (void*)&b_out_coord,
        (void*)&pre, (void*)&out
    };
    hipError_t ce = hipLaunchCooperativeKernel((const void*)lstm_main, dim3(128), dim3(256),
                                               args, 0, stream);
    if (ce != hipSuccess) {
        // plain launch: 128 blocks <= 256 CUs -> always fully co-resident.
        lstm_main<<<dim3(128), dim3(256), 0, stream>>>(
            x, wpackF, wheadF, weff_c, weff_x, biasE_c, biasE_x, ring,
            b_out_cmd, b_out_coord, pre, out);
    }

    coord_post<<<1536, 256, 0, stream>>>(w_out_coord, scale, out);
}

// Round 11
// 3717.958 us; speedup vs baseline: 1.5322x; 1.5322x over previous
//
#include <hip/hip_runtime.h>
#include <hip/hip_bf16.h>
#include <math.h>

#define TSTEPS 1024

typedef __attribute__((ext_vector_type(8))) short short8;
typedef __attribute__((ext_vector_type(4))) float f32x4;
typedef __attribute__((ext_vector_type(4))) unsigned u32x4;

// ---- workspace layout (float units) ----
#define WS_BAR     0
#define WS_WEFF_C  1024
#define WS_WEFF_X  (WS_WEFF_C + 20480)
#define WS_BIAS_C  (WS_WEFF_X + 12288)
#define WS_BIAS_X  (WS_BIAS_C + 131072)
#define WS_HRING   (WS_BIAS_X + 131072)    // uints: 8 islands * 8 slots * 8192 = 524288 (2MB, memset/launch)
#define WS_WPACK   (WS_HRING + 524288)     // shorts: 4194304 -> 2097152 floats
#define WS_WHEAD   (WS_WPACK + 2097152)    // shorts: 16384 -> 8192 floats

__device__ __forceinline__ float sigm(float v) { return 1.f / (1.f + __expf(-v)); }

// LDS-only barrier: order ds ops without draining in-flight global stores.
__device__ __forceinline__ void bar_lds() {
    asm volatile("s_waitcnt lgkmcnt(0)\n\ts_barrier" ::: "memory");
}

// ---------------- setup 1: effective input weights + per-batch bias (validated R1-R8) ----------------
__global__ void setup_weff_bias(const float* __restrict__ ctx,
                                const float* __restrict__ we_c, const float* __restrict__ be_c,
                                const float* __restrict__ we_x, const float* __restrict__ be_x,
                                const float* __restrict__ wih_c, const float* __restrict__ bih_c, const float* __restrict__ bhh_c,
                                const float* __restrict__ wih_x, const float* __restrict__ bih_x, const float* __restrict__ bhh_x,
                                float* __restrict__ weff_c_o, float* __restrict__ weff_x_o,
                                float* __restrict__ biasE_c_o, float* __restrict__ biasE_x_o)
{
    const int g = blockIdx.x;
    const int lstm = blockIdx.y;
    const int tid = threadIdx.x;
    const float* wih  = lstm ? wih_x : wih_c;
    const float* wemb = lstm ? we_x  : we_c;
    const float* bemb = lstm ? be_x  : be_c;
    const int NW = lstm ? 6 : 10;
    float* weff  = lstm ? weff_x_o  : weff_c_o;
    float* biasE = lstm ? biasE_x_o : biasE_c_o;
    const float* wg_ = wih + (size_t)g * 768;

    __shared__ float s_bias0;

    if (tid < NW) {
        float s = 0.f;
        for (int d = 0; d < 512; ++d) s = fmaf(wg_[d], wemb[d * NW + tid], s);
        weff[g * NW + tid] = s;
    }
    if (tid >= 64 && tid < 128) {
        int l = tid - 64;
        float s = 0.f;
        for (int i = 0; i < 8; ++i) { int d = l + i * 64; s = fmaf(wg_[d], bemb[d], s); }
        for (int m = 1; m < 64; m <<= 1) s += __shfl_xor(s, m);
        if (l == 0) s_bias0 = s;
    }
    __syncthreads();
    if (tid >= 128 && tid < 192) {
        int b = tid - 128;
        float s = s_bias0 + (lstm ? (bih_x[g] + bhh_x[g]) : (bih_c[g] + bhh_c[g]));
        const float* cb = ctx + b * 256;
        const float* wc = wg_ + 512;
        for (int c = 0; c < 256; ++c) s = fmaf(wc[c], cb[c], s);
        biasE[b * 2048 + g] = s;
    }
}

// ---------------- setup 2: pack W_hh into MFMA B-frag layout, bf16 hi/lo (validated R3-R8) ----------------
__global__ void setup_wpackF(const float* __restrict__ whh_c, const float* __restrict__ whh_x,
                             short* __restrict__ wpackF)
{
    int idx = blockIdx.x * 256 + threadIdx.x;      // 2^21 total
    int pos = idx & 511;
    int lane = pos >> 3, j = pos & 7;
    int kt4 = (idx >> 9) & 3;
    int q   = (idx >> 11) & 3;
    int wv  = (idx >> 13) & 3;
    int ub  = (idx >> 15) & 31;
    int lstm = (idx >> 20) & 1;
    int g = q * 512 + ub * 16 + (lane & 15);
    int k = wv * 128 + kt4 * 32 + (lane >> 4) * 8 + j;
    const float* whh = lstm ? whh_x : whh_c;
    float v = whh[(size_t)g * 512 + k];
    __hip_bfloat16 hi = __float2bfloat16(v);
    __hip_bfloat16 lo = __float2bfloat16(v - __bfloat162float(hi));
    size_t base = (size_t)(idx >> 9) * 1024 + pos;
    wpackF[base]       = __builtin_bit_cast(short, hi);
    wpackF[base + 512] = __builtin_bit_cast(short, lo);
}

// ---------------- setup 3: pack head weights into B-frag layout (hi only, validated R8) ----------------
__global__ void setup_wheadF(const float* __restrict__ w_out_cmd,
                             const float* __restrict__ w_out_coord,
                             short* __restrict__ wheadF)
{
    int idx = blockIdx.x * 256 + threadIdx.x;      // 16384 total
    int lstm = idx >> 13;
    int rest = idx & 8191;
    int wv = rest >> 11;
    int k4 = (rest >> 9) & 3;
    int pos = rest & 511;
    int lane = pos >> 3, jj = pos & 7;
    int j = lane & 15;
    int k = wv * 128 + k4 * 32 + (lane >> 4) * 8 + jj;
    int NJ = lstm ? 6 : 10;
    float v = 0.f;
    if (j < NJ) v = lstm ? w_out_coord[(size_t)j * 522 + k] : w_out_cmd[(size_t)j * 512 + k];
    wheadF[idx] = __builtin_bit_cast(short, __float2bfloat16(v));
}

// ---------------- main persistent kernel: flagless epoch-tagged data polling (R8, best measured) ----------------
// Island = (lstm, bt): 32 WGs. Ring: depth 8, packed uint per h value:
// bits0-15 = bf16 hi, bits16-31 = bf16 lo with its 2 LSBs REPLACED by tag = 1+((t>>3)&1).
// Consumers retry wide coherent loads until all words carry the expected tag -> sync==data, 1 RT.
// Producers: relaxed agent atomic stores, NO flag, NO drain. LDS barriers are lgkm-only.
// Heads: ub==0 WG computes cmd/coord head via 4 extra MFMAs on its own A-frags (hi-only).
__global__ __launch_bounds__(256, 2) void lstm_main(
    const float* __restrict__ x,
    const short* __restrict__ wpackF,
    const short* __restrict__ wheadF,
    const float* __restrict__ weff_c, const float* __restrict__ weff_x,
    const float* __restrict__ biasE_c, const float* __restrict__ biasE_x,
    unsigned* __restrict__ ring,
    const float* __restrict__ b_out_cmd, const float* __restrict__ b_out_coord,
    float* __restrict__ pre_coord,
    float* __restrict__ out)
{
    __shared__ float lds_gp[4][4][16][17];      // [wv][q][b][u] gate partials
    __shared__ float lds_hp[4][16][17];         // [wv][b][j]    head partials
    __shared__ float x_lds[16][10];
    __shared__ float weff_lds[4][16][10];
    __shared__ short whd_lds[4][4][512];        // head B-frags [wv][k4][...]

    const int tid = threadIdx.x;
    const int bid = blockIdx.x;
    const int lane = tid & 63;
    const int wv = tid >> 6;
    const int lstm = bid >> 7;
    const int ub = (bid >> 2) & 31;
    const int bt = bid & 3;
    const int island = lstm * 4 + bt;
    const int u0 = ub * 16, b0 = bt * 16;
    const int NW = lstm ? 6 : 10;
    const int xoff = lstm ? 10 : 0;
    const int u_l = tid & 15, b_l = tid >> 4;

    const float* weff  = lstm ? weff_x : weff_c;
    const float* biasE = lstm ? biasE_x : biasE_c;

    unsigned* ring_isl = ring + island * 8 * 8192;   // 8 slots x 8192 uints

    // ---- one-time: recurrent weight frags into registers/AGPRs ----
    const short* wb = wpackF + (size_t)(((lstm * 32 + ub) * 4 + wv) * 16) * 1024 + lane * 8;
    short8 W[4][4][2];
#pragma unroll
    for (int q = 0; q < 4; ++q)
#pragma unroll
        for (int k4 = 0; k4 < 4; ++k4) {
            W[q][k4][0] = *(const short8*)(wb + (q * 4 + k4) * 1024);
            W[q][k4][1] = *(const short8*)(wb + (q * 4 + k4) * 1024 + 512);
        }

    float biasr[4];
#pragma unroll
    for (int q = 0; q < 4; ++q)
        biasr[q] = biasE[(size_t)(b0 + b_l) * 2048 + q * 512 + u0 + u_l];

    for (int i = tid; i < 64 * NW; i += 256) {
        int r = i / NW, j = i - r * NW;
        weff_lds[r >> 4][r & 15][j] = weff[(size_t)((r >> 4) * 512 + u0 + (r & 15)) * NW + j];
    }

    // head bias + head weight frags (ub==0 WGs only use them, stage anyway if ub==0)
    float hbias = 0.f;
    const int NJ = lstm ? 6 : 10;
    if (ub == 0) {
        if (u_l < NJ) hbias = lstm ? b_out_coord[u_l] : b_out_cmd[u_l];
        const short* src = wheadF + lstm * 8192;
        short* dst = &whd_lds[0][0][0];
        for (int i = tid; i < 8192; i += 256) dst[i] = src[i];
    }

    float c_reg = 0.f;
    __syncthreads();   // one-time staging barrier

    for (int t = 0; t <= TSTEPS; ++t) {
        const bool last = (t == TSTEPS);
        if (last && ub != 0) break;   // only head-writer WGs run the final head-only step

        // ---- x prefetch for step t (static input; drained by the retry-load's vmcnt) ----
        float xv = 0.f;
        int xb = 0, xj = 0;
        const bool hasx = !last && (tid < 16 * NW);
        if (hasx) {
            xb = tid / NW; xj = tid - xb * NW;
            xv = x[(size_t)((b0 + xb) * TSTEPS + t) * 16 + xoff + xj];
        }

        // ---- A-frags: epoch-tagged retry load of h_{t-1} (sync == data, one RT) ----
        short8 Ah[4], Al[4];
        if (t > 0) {
            const unsigned rtag = 1u + (((unsigned)(t - 1) >> 3) & 1u);
            const unsigned* rb = ring_isl + ((t + 7) & 7) * 8192 + lane * 8;
            const unsigned* p0 = rb + (wv * 4 + 0) * 512;
            const unsigned* p1 = rb + (wv * 4 + 1) * 512;
            const unsigned* p2 = rb + (wv * 4 + 2) * 512;
            const unsigned* p3 = rb + (wv * 4 + 3) * 512;
            u32x4 r0, r1, r2, r3, r4, r5, r6, r7;
            while (true) {
                asm volatile(
                    "global_load_dwordx4 %0, %8, off sc0 sc1\n\t"
                    "global_load_dwordx4 %1, %8, off offset:16 sc0 sc1\n\t"
                    "global_load_dwordx4 %2, %9, off sc0 sc1\n\t"
                    "global_load_dwordx4 %3, %9, off offset:16 sc0 sc1\n\t"
                    "global_load_dwordx4 %4, %10, off sc0 sc1\n\t"
                    "global_load_dwordx4 %5, %10, off offset:16 sc0 sc1\n\t"
                    "global_load_dwordx4 %6, %11, off sc0 sc1\n\t"
                    "global_load_dwordx4 %7, %11, off offset:16 sc0 sc1\n\t"
                    "s_waitcnt vmcnt(0)"
                    : "=&v"(r0), "=&v"(r1), "=&v"(r2), "=&v"(r3),
                      "=&v"(r4), "=&v"(r5), "=&v"(r6), "=&v"(r7)
                    : "v"(p0), "v"(p1), "v"(p2), "v"(p3)
                    : "memory");
                bool ok = true;
#pragma unroll
                for (int e = 0; e < 4; ++e) {
                    ok = ok && (((r0[e] >> 16) & 3u) == rtag) && (((r1[e] >> 16) & 3u) == rtag)
                            && (((r2[e] >> 16) & 3u) == rtag) && (((r3[e] >> 16) & 3u) == rtag)
                            && (((r4[e] >> 16) & 3u) == rtag) && (((r5[e] >> 16) & 3u) == rtag)
                            && (((r6[e] >> 16) & 3u) == rtag) && (((r7[e] >> 16) & 3u) == rtag);
                }
                if (__all((int)ok)) break;
            }
            unsigned uu[4][8];
#pragma unroll
            for (int e = 0; e < 4; ++e) {
                uu[0][e] = r0[e]; uu[0][4 + e] = r1[e];
                uu[1][e] = r2[e]; uu[1][4 + e] = r3[e];
                uu[2][e] = r4[e]; uu[2][4 + e] = r5[e];
                uu[3][e] = r6[e]; uu[3][4 + e] = r7[e];
            }
#pragma unroll
            for (int i = 0; i < 4; ++i) {
                union { unsigned u[4]; short8 s; } ah, al;
                ah.u[0] = __builtin_amdgcn_perm(uu[i][1], uu[i][0], 0x05040100u);
                ah.u[1] = __builtin_amdgcn_perm(uu[i][3], uu[i][2], 0x05040100u);
                ah.u[2] = __builtin_amdgcn_perm(uu[i][5], uu[i][4], 0x05040100u);
                ah.u[3] = __builtin_amdgcn_perm(uu[i][7], uu[i][6], 0x05040100u);
                al.u[0] = __builtin_amdgcn_perm(uu[i][1], uu[i][0], 0x07060302u);
                al.u[1] = __builtin_amdgcn_perm(uu[i][3], uu[i][2], 0x07060302u);
                al.u[2] = __builtin_amdgcn_perm(uu[i][5], uu[i][4], 0x07060302u);
                al.u[3] = __builtin_amdgcn_perm(uu[i][7], uu[i][6], 0x07060302u);
                Ah[i] = ah.s;
                Al[i] = al.s;
            }
        }

        // ---- gates MFMA ----
        if (!last) {
            f32x4 C[4];
#pragma unroll
            for (int q = 0; q < 4; ++q) { C[q][0] = 0.f; C[q][1] = 0.f; C[q][2] = 0.f; C[q][3] = 0.f; }
            if (t > 0) {
#pragma unroll
                for (int q = 0; q < 4; ++q)
#pragma unroll
                    for (int i = 0; i < 4; ++i) {
                        C[q] = __builtin_amdgcn_mfma_f32_16x16x32_bf16(Ah[i], W[q][i][0], C[q], 0, 0, 0);
                        C[q] = __builtin_amdgcn_mfma_f32_16x16x32_bf16(Al[i], W[q][i][0], C[q], 0, 0, 0);
                        C[q] = __builtin_amdgcn_mfma_f32_16x16x32_bf16(Ah[i], W[q][i][1], C[q], 0, 0, 0);
                    }
            }
#pragma unroll
            for (int q = 0; q < 4; ++q)
#pragma unroll
                for (int i = 0; i < 4; ++i)
                    lds_gp[wv][q][(lane >> 4) * 4 + i][lane & 15] = C[q][i];
        }

        // ---- head MFMA (writer WG only): reuses this WG's A-frags, hi-only ----
        if (ub == 0 && t > 0) {
            short8 Whd[4];
#pragma unroll
            for (int i = 0; i < 4; ++i)
                Whd[i] = *(const short8*)&whd_lds[wv][i][lane * 8];
            f32x4 Ch; Ch[0] = 0.f; Ch[1] = 0.f; Ch[2] = 0.f; Ch[3] = 0.f;
#pragma unroll
            for (int i = 0; i < 4; ++i)
                Ch = __builtin_amdgcn_mfma_f32_16x16x32_bf16(Ah[i], Whd[i], Ch, 0, 0, 0);
#pragma unroll
            for (int i = 0; i < 4; ++i)
                lds_hp[wv][(lane >> 4) * 4 + i][lane & 15] = Ch[i];
        }

        if (hasx) x_lds[xb][xj] = xv;
        bar_lds();   // join: partials + x visible

        // ---- gate epilogue + cell update + tagged ring store ----
        if (!last) {
            float g4[4];
#pragma unroll
            for (int q = 0; q < 4; ++q) {
                float s = biasr[q];
                s += lds_gp[0][q][b_l][u_l] + lds_gp[1][q][b_l][u_l]
                   + lds_gp[2][q][b_l][u_l] + lds_gp[3][q][b_l][u_l];
                for (int j = 0; j < NW; ++j)
                    s = fmaf(weff_lds[q][u_l][j], x_lds[b_l][j], s);
                g4[q] = s;
            }
            float iv = sigm(g4[0]);
            float fv = sigm(g4[1]);
            float gv = tanhf(g4[2]);
            float ov = sigm(g4[3]);
            c_reg = fmaf(fv, c_reg, iv * gv);
            float hv = ov * tanhf(c_reg);
            __hip_bfloat16 hh = __float2bfloat16(hv);
            __hip_bfloat16 hl = __float2bfloat16(hv - __bfloat162float(hh));
            {
                const unsigned wtag = 1u + (((unsigned)t >> 3) & 1u);
                int ug = u0 + u_l;
                int kt = ug >> 5, ko = ug & 31;
                unsigned pack = (unsigned)(unsigned short)__builtin_bit_cast(short, hh)
                              | ((unsigned)(unsigned short)__builtin_bit_cast(short, hl) << 16);
                pack = (pack & ~0x00030000u) | (wtag << 16);
                unsigned idx = (unsigned)((t & 7) * 8192 + kt * 512
                             + ((ko >> 3) * 16 + b_l) * 8 + (ko & 7));
                __hip_atomic_store(&ring_isl[idx], pack, __ATOMIC_RELAXED, __HIP_MEMORY_SCOPE_AGENT);
            }
        }

        // ---- head epilogue (writer WG): h_{t-1} heads, no extra loads ----
        if (ub == 0 && t > 0 && u_l < NJ) {
            float hs = lds_hp[0][b_l][u_l] + lds_hp[1][b_l][u_l]
                     + lds_hp[2][b_l][u_l] + lds_hp[3][b_l][u_l] + hbias;
            const int tc = t - 1;
            if (lstm == 0)
                out[(size_t)((b0 + b_l) * TSTEPS + tc) * 10 + u_l] = hs;
            else
                pre_coord[(size_t)((b0 + b_l) * TSTEPS + tc) * 6 + u_l] = hs;
        }

        bar_lds();   // protect LDS reuse before next iteration's writes
    }
}

// ---------------- post: coord output = tanh(scale * (pre + cmd-coupling)), in place ----------------
__global__ void coord_post(const float* __restrict__ w_oc,
                           const float* __restrict__ scale_p, float* __restrict__ out)
{
    int idx = blockIdx.x * 256 + threadIdx.x;
    if (idx >= 64 * TSTEPS * 6) return;
    int j = idx % 6, bt_ = idx / 6;
    float s = out[64 * TSTEPS * 10 + idx];
    const float* cmd = out + (size_t)bt_ * 10;
#pragma unroll
    for (int i = 0; i < 10; ++i) s = fmaf(cmd[i], w_oc[j * 522 + 512 + i], s);
    out[64 * TSTEPS * 10 + idx] = tanhf(s * scale_p[0]);
}

// ---------------- host launcher ----------------
extern "C" void kernel_launch(void* const* d_in, const int* in_sizes, int n_in,
                              void* d_out, int out_size, void* d_ws, size_t ws_size,
                              hipStream_t stream)
{
    const float* x            = (const float*)d_in[0];
    const float* context      = (const float*)d_in[1];
    const float* w_cmd_emb    = (const float*)d_in[2];
    const float* b_cmd_emb    = (const float*)d_in[3];
    const float* w_coord_emb  = (const float*)d_in[4];
    const float* b_coord_emb  = (const float*)d_in[5];
    const float* w_ih_cmd     = (const float*)d_in[6];
    const float* w_hh_cmd     = (const float*)d_in[7];
    const float* b_ih_cmd     = (const float*)d_in[8];
    const float* b_hh_cmd     = (const float*)d_in[9];
    const float* w_ih_coord   = (const float*)d_in[10];
    const float* w_hh_coord   = (const float*)d_in[11];
    const float* b_ih_coord   = (const float*)d_in[12];
    const float* b_hh_coord   = (const float*)d_in[13];
    const float* w_out_cmd    = (const float*)d_in[14];
    const float* b_out_cmd    = (const float*)d_in[15];
    const float* w_out_coord  = (const float*)d_in[16];
    const float* b_out_coord  = (const float*)d_in[17];
    const float* scale        = (const float*)d_in[18];

    float* ws  = (float*)d_ws;
    float* out = (float*)d_out;

    float* weff_c   = ws + WS_WEFF_C;
    float* weff_x   = ws + WS_WEFF_X;
    float* biasE_c  = ws + WS_BIAS_C;
    float* biasE_x  = ws + WS_BIAS_X;
    unsigned* ring  = (unsigned*)(ws + WS_HRING);
    short* wpackF   = (short*)(ws + WS_WPACK);
    short* wheadF   = (short*)(ws + WS_WHEAD);
    float* pre      = out + 64 * TSTEPS * 10;   // coord pre-activations live in out tail

    // zero the h ring every launch: tag bits of zeroed words (=0) never match tags {1,2}
    hipMemsetAsync(ring, 0, 8 * 8 * 8192 * sizeof(unsigned), stream);

    setup_weff_bias<<<dim3(2048, 2), 256, 0, stream>>>(
        context, w_cmd_emb, b_cmd_emb, w_coord_emb, b_coord_emb,
        w_ih_cmd, b_ih_cmd, b_hh_cmd,
        w_ih_coord, b_ih_coord, b_hh_coord,
        weff_c, weff_x, biasE_c, biasE_x);

    setup_wpackF<<<8192, 256, 0, stream>>>(w_hh_cmd, w_hh_coord, wpackF);
    setup_wheadF<<<64, 256, 0, stream>>>(w_out_cmd, w_out_coord, wheadF);

    void* args[] = {
        (void*)&x, (void*)&wpackF, (void*)&wheadF,
        (void*)&weff_c, (void*)&weff_x,
        (void*)&biasE_c, (void*)&biasE_x,
        (void*)&ring,
        (void*)&b_out_cmd, (void*)&b_out_coord,
        (void*)&pre, (void*)&out
    };
    hipError_t ce = hipLaunchCooperativeKernel((const void*)lstm_main, dim3(256), dim3(256),
                                               args, 0, stream);
    if (ce != hipSuccess) {
        // plain launch: with __launch_bounds__(256,2) any 2 WGs fit per CU, so all
        // 256 blocks are co-resident on 256 CUs regardless of distribution.
        lstm_main<<<dim3(256), dim3(256), 0, stream>>>(
            x, wpackF, wheadF, weff_c, weff_x, biasE_c, biasE_x, ring,
            b_out_cmd, b_out_coord, pre, out);
    }

    coord_post<<<1536, 256, 0, stream>>>(w_out_coord, scale, out);
}